// Round 1
// baseline (296.334 us; speedup 1.0000x reference)
//
#include <hip/hip_runtime.h>
#include <stdint.h>

typedef unsigned int u32;
typedef unsigned long long u64;
typedef unsigned short u16;
typedef __attribute__((ext_vector_type(8))) __bf16 bf16x8;
typedef __attribute__((ext_vector_type(4))) float f32x4;

#define DEV __device__ __forceinline__

// f32 -> bf16 RTNE (finite values only; fine for this workload)
DEV u16 f2bf(float f) {
    u32 x = __builtin_bit_cast(u32, f);
    u32 r = (x + 0x7FFFu + ((x >> 16) & 1u)) >> 16;
    return (u16)r;
}

DEV bf16x8 ldg8(const u16* p) {
    return __builtin_bit_cast(bf16x8, *(const uint4*)p);
}

DEV u32 pk2(float a, float b) {
    return (u32)f2bf(a) | ((u32)f2bf(b) << 16);
}

DEV void g2l16(const u16* g, u16* l) {
    __builtin_amdgcn_global_load_lds(
        (const __attribute__((address_space(1))) u32*)g,
        (__attribute__((address_space(3))) u32*)l, 16, 0, 0);
}

DEV f32x4 mfma16(bf16x8 a, bf16x8 b, f32x4 c) {
    return __builtin_amdgcn_mfma_f32_16x16x32_bf16(a, b, c, 0, 0, 0);
}

// ---------------------------------------------------------------- mask pack
// tgt_mask [4M] + memory_mask [4M] int32 -> 1 bit each
__global__ __launch_bounds__(256) void packmask_kernel(
    const int* __restrict__ m1, const int* __restrict__ m2,
    u32* __restrict__ o1, u32* __restrict__ o2, int n) {
    int i = blockIdx.x * 256 + threadIdx.x;
    bool first = i < n;
    int idx = first ? i : i - n;
    int v = first ? m1[idx] : m2[idx];
    u64 bal = __ballot(v != 0);
    if ((threadIdx.x & 31) == 0) {
        u32 w = (u32)(bal >> (threadIdx.x & 32));
        (first ? o1 : o2)[idx >> 5] = w;
    }
}

// ---------------------------------------------------------------- prep casts
// qin=bf16(tgt+tpos), tgtb=bf16(tgt), memb=bf16(mem), mkb=bf16(mem+mpos)
__global__ __launch_bounds__(256) void prep_kernel(
    const float4* __restrict__ tgt, const float4* __restrict__ tpos,
    const float4* __restrict__ mem, const float4* __restrict__ mpos,
    ushort4* __restrict__ qin, ushort4* __restrict__ tgtb,
    ushort4* __restrict__ memb, ushort4* __restrict__ mkb, int n4) {
    int i = blockIdx.x * 256 + threadIdx.x;
    if (i >= n4) return;
    float4 t = tgt[i], p = tpos[i], m = mem[i], mp = mpos[i];
    qin[i]  = make_ushort4(f2bf(t.x + p.x), f2bf(t.y + p.y), f2bf(t.z + p.z), f2bf(t.w + p.w));
    tgtb[i] = make_ushort4(f2bf(t.x), f2bf(t.y), f2bf(t.z), f2bf(t.w));
    memb[i] = make_ushort4(f2bf(m.x), f2bf(m.y), f2bf(m.z), f2bf(m.w));
    mkb[i]  = make_ushort4(f2bf(m.x + mp.x), f2bf(m.y + mp.y), f2bf(m.z + mp.z), f2bf(m.w + mp.w));
}

// ---------------------------------------------------------------- weight transpose
// 10 weights f32 [K][N] -> bf16 W^T [N][K]
struct W10 { const float* w[10]; };
__global__ __launch_bounds__(256) void wtrans_kernel(W10 ws, u16* wtbase) {
    int z = blockIdx.y;
    int Kd = (z == 9) ? 2048 : 512;
    int Nd = (z == 8) ? 2048 : 512;
    size_t off = (z < 8) ? (size_t)z * 262144
                         : (z == 8 ? (size_t)2097152 : (size_t)3145728);
    u16* out = wtbase + off;
    int nx = Nd / 32;
    int txile = blockIdx.x % nx, tyile = blockIdx.x / nx;
    if (tyile >= Kd / 32) return;
    const float* w = ws.w[z];
    __shared__ float t[32][33];
    int tx = threadIdx.x, ty = threadIdx.y;
#pragma unroll
    for (int j = 0; j < 4; ++j)
        t[ty + j * 8][tx] = w[(size_t)(tyile * 32 + ty + j * 8) * Nd + txile * 32 + tx];
    __syncthreads();
#pragma unroll
    for (int j = 0; j < 4; ++j)
        out[(size_t)(txile * 32 + ty + j * 8) * Kd + tyile * 32 + tx] = f2bf(t[tx][ty + j * 8]);
}

// ---------------------------------------------------------------- V transpose
// V bf16 [B*L][512] -> VT bf16 [B][8][64][L]
__global__ __launch_bounds__(256) void vtrans_kernel(
    const u16* __restrict__ V, u16* __restrict__ VT, int L) {
    int z = blockIdx.z, b = z >> 3, h = z & 7;
    int s0 = blockIdx.x * 32, d0 = blockIdx.y * 32;
    __shared__ u16 t[32][33];
    int tx = threadIdx.x, ty = threadIdx.y;
#pragma unroll
    for (int j = 0; j < 4; ++j)
        t[ty + j * 8][tx] = V[(size_t)(b * L + s0 + ty + j * 8) * 512 + h * 64 + d0 + tx];
    __syncthreads();
#pragma unroll
    for (int j = 0; j < 4; ++j)
        VT[((size_t)z * 64 + d0 + ty + j * 8) * L + s0 + tx] = t[tx][ty + j * 8];
}

// ---------------------------------------------------------------- GEMM
// C[M][N] = A[M][K](bf16) @ W^T[N][K](bf16) + bias, EPI: 0 bf16, 1 bf16+relu, 2 f32
struct GemmSet { const u16* A; const u16* W; const float* bias; void* out; };
struct GemmArgs3 { GemmSet s[3]; };

template <int EPI>
__global__ __launch_bounds__(256) void gemm_kernel(GemmArgs3 args, int M, int N, int Kd) {
    const GemmSet gs = args.s[blockIdx.z];
    const u16* __restrict__ A = gs.A;
    const u16* __restrict__ W = gs.W;
    const int t = threadIdx.x;
    const int lane = t & 63, wave = t >> 6;
    const int g = lane >> 4, r16 = lane & 15;
    const int wm = wave >> 1, wn = wave & 1;
    const int m0 = blockIdx.y * 128, n0 = blockIdx.x * 64;

    __shared__ __align__(16) u16 As[128 * 64];
    __shared__ __align__(16) u16 Bs[64 * 64];

    f32x4 acc[4][2];
#pragma unroll
    for (int m = 0; m < 4; ++m)
#pragma unroll
        for (int n = 0; n < 2; ++n) acc[m][n] = f32x4{0.f, 0.f, 0.f, 0.f};

    for (int kk = 0; kk < Kd; kk += 64) {
        __syncthreads();
#pragma unroll
        for (int i = 0; i < 4; ++i) {
            int cid = t + i * 256, row = cid >> 3, c = cid & 7;
            g2l16(A + (size_t)(m0 + row) * Kd + kk + ((c ^ (row & 7)) << 3), &As[cid << 3]);
        }
#pragma unroll
        for (int i = 0; i < 2; ++i) {
            int cid = t + i * 256, row = cid >> 3, c = cid & 7;
            g2l16(W + (size_t)(n0 + row) * Kd + kk + ((c ^ (row & 7)) << 3), &Bs[cid << 3]);
        }
        __syncthreads();
#pragma unroll
        for (int ks = 0; ks < 2; ++ks) {
            bf16x8 af[4], bfr[2];
#pragma unroll
            for (int m = 0; m < 4; ++m) {
                int row = wm * 64 + m * 16 + r16;
                af[m] = *(const bf16x8*)&As[(row << 6) + (((ks * 4 + g) ^ (row & 7)) << 3)];
            }
#pragma unroll
            for (int n = 0; n < 2; ++n) {
                int row = wn * 32 + n * 16 + r16;
                bfr[n] = *(const bf16x8*)&Bs[(row << 6) + (((ks * 4 + g) ^ (row & 7)) << 3)];
            }
#pragma unroll
            for (int m = 0; m < 4; ++m)
#pragma unroll
                for (int n = 0; n < 2; ++n)
                    acc[m][n] = mfma16(af[m], bfr[n], acc[m][n]);
        }
    }
#pragma unroll
    for (int m = 0; m < 4; ++m) {
        int row0 = m0 + wm * 64 + m * 16 + g * 4;
#pragma unroll
        for (int n = 0; n < 2; ++n) {
            int col = n0 + wn * 32 + n * 16 + r16;
            float bv = gs.bias[col];
#pragma unroll
            for (int r = 0; r < 4; ++r) {
                float v = acc[m][n][r] + bv;
                if (EPI == 1) v = fmaxf(v, 0.f);
                size_t idx = (size_t)(row0 + r) * N + col;
                if (EPI == 2) ((float*)gs.out)[idx] = v;
                else ((u16*)gs.out)[idx] = f2bf(v);
            }
        }
    }
}

// ---------------------------------------------------------------- attention
// Q,K bf16 [B*L][512]; VT bf16 [B][8][64][Lk]; mb bitmask; O bf16 [B*Lq][512]
// scores = (QK^T)/8 ; masked -> 1e-9 ; softmax ; PV.  One wave = 16 q rows.
__global__ __launch_bounds__(256) void attn_kernel(
    const u16* __restrict__ Q, const u16* __restrict__ K,
    const u16* __restrict__ VT, const u32* __restrict__ mb,
    u16* __restrict__ O, int Lq, int Lk) {
    const int t = threadIdx.x, lane = t & 63, wave = t >> 6;
    const int g = lane >> 4, r16 = lane & 15;
    const int h = blockIdx.y, b = blockIdx.z;
    const int q0 = blockIdx.x * 64 + wave * 16;
    const int D = 512;
    __shared__ __align__(16) u16 Pl[4][16][40];  // row stride 80B (16B-aligned frags)
    __shared__ float Al[4][16];

    const size_t qrow = (size_t)b * Lq + q0 + r16;
    const u16* qp = Q + qrow * D + h * 64 + g * 8;
    bf16x8 qb0 = ldg8(qp);
    bf16x8 qb1 = ldg8(qp + 32);
    const u32* mrow = mb + qrow * (Lk >> 5);

    f32x4 acc[4];
#pragma unroll
    for (int dt = 0; dt < 4; ++dt) acc[dt] = f32x4{0.f, 0.f, 0.f, 0.f};
    float mrun = -INFINITY, lrun = 0.f;
    const f32x4 zf = {0.f, 0.f, 0.f, 0.f};

    const u16* kb_base = K + (size_t)b * Lk * D + h * 64 + g * 8;
    const u16* vt_base = VT + ((size_t)(b * 8 + h) * 64 + r16) * Lk + g * 8;

    for (int kc = 0; kc < Lk; kc += 32) {
        const u16* kp = kb_base + (size_t)(kc + r16) * D;
        bf16x8 ka0 = ldg8(kp);
        bf16x8 ka1 = ldg8(kp + 32);
        bf16x8 ka2 = ldg8(kp + (size_t)16 * D);
        bf16x8 ka3 = ldg8(kp + (size_t)16 * D + 32);
        f32x4 s0 = mfma16(ka0, qb0, zf); s0 = mfma16(ka1, qb1, s0);
        f32x4 s1 = mfma16(ka2, qb0, zf); s1 = mfma16(ka3, qb1, s1);
        u32 mw = mrow[kc >> 5];
        float sv[8];
#pragma unroll
        for (int r = 0; r < 4; ++r) {
            int k1 = g * 4 + r, k2 = 16 + g * 4 + r;
            sv[r]     = ((mw >> k1) & 1) ? s0[r] * 0.125f : 1e-9f;
            sv[4 + r] = ((mw >> k2) & 1) ? s1[r] * 0.125f : 1e-9f;
        }
        float tm = sv[0];
#pragma unroll
        for (int j = 1; j < 8; ++j) tm = fmaxf(tm, sv[j]);
        tm = fmaxf(tm, __shfl_xor(tm, 16));
        tm = fmaxf(tm, __shfl_xor(tm, 32));
        float mn = fmaxf(mrun, tm);
        float alpha = __expf(mrun - mn);
        mrun = mn;
        float ts = 0.f;
#pragma unroll
        for (int j = 0; j < 8; ++j) { sv[j] = __expf(sv[j] - mn); ts += sv[j]; }
        ts += __shfl_xor(ts, 16);
        ts += __shfl_xor(ts, 32);
        lrun = lrun * alpha + ts;
        uint2 u01; u01.x = pk2(sv[0], sv[1]); u01.y = pk2(sv[2], sv[3]);
        uint2 u23; u23.x = pk2(sv[4], sv[5]); u23.y = pk2(sv[6], sv[7]);
        *(uint2*)&Pl[wave][r16][g * 4] = u01;
        *(uint2*)&Pl[wave][r16][16 + g * 4] = u23;
        if (lane < 16) Al[wave][lane] = alpha;
        float ar0 = Al[wave][g * 4 + 0], ar1 = Al[wave][g * 4 + 1];
        float ar2 = Al[wave][g * 4 + 2], ar3 = Al[wave][g * 4 + 3];
#pragma unroll
        for (int dt = 0; dt < 4; ++dt) {
            acc[dt][0] *= ar0; acc[dt][1] *= ar1; acc[dt][2] *= ar2; acc[dt][3] *= ar3;
        }
        bf16x8 pf = *(const bf16x8*)&Pl[wave][r16][g * 8];
#pragma unroll
        for (int dt = 0; dt < 4; ++dt) {
            bf16x8 vf = ldg8(vt_base + (size_t)dt * 16 * Lk + kc);
            acc[dt] = mfma16(pf, vf, acc[dt]);
        }
    }
    if (lane < 16) Al[wave][lane] = lrun;
    float li[4];
#pragma unroll
    for (int r = 0; r < 4; ++r) li[r] = 1.f / Al[wave][g * 4 + r];
    const size_t obase = ((size_t)b * Lq + q0) * D + h * 64;
#pragma unroll
    for (int dt = 0; dt < 4; ++dt)
#pragma unroll
        for (int r = 0; r < 4; ++r)
            O[obase + (size_t)(g * 4 + r) * D + dt * 16 + r16] = f2bf(acc[dt][r] * li[r]);
}

// ---------------------------------------------------------------- LayerNorm
// y = LN(a + bsrc)*g + b ; MODE 0: yf,yb,qb=bf16(y+pos) ; 1: yf,yb ; 2: yf only
template <int MODE>
__global__ __launch_bounds__(256) void ln_kernel(
    const float* __restrict__ a, const float* __restrict__ bsrc,
    const float* __restrict__ gam, const float* __restrict__ bet,
    const float* __restrict__ pos,
    float* __restrict__ yf, u16* __restrict__ yb, u16* __restrict__ qb) {
    const int lane = threadIdx.x & 63;
    const int row = blockIdx.x * 4 + (threadIdx.x >> 6);
    const size_t base = (size_t)row * 512 + lane * 8;
    float4 av0 = ((const float4*)(a + base))[0];
    float4 av1 = ((const float4*)(a + base))[1];
    float4 bv0 = ((const float4*)(bsrc + base))[0];
    float4 bv1 = ((const float4*)(bsrc + base))[1];
    float x[8] = {av0.x + bv0.x, av0.y + bv0.y, av0.z + bv0.z, av0.w + bv0.w,
                  av1.x + bv1.x, av1.y + bv1.y, av1.z + bv1.z, av1.w + bv1.w};
    float s1 = 0.f, s2 = 0.f;
#pragma unroll
    for (int j = 0; j < 8; ++j) { s1 += x[j]; s2 += x[j] * x[j]; }
#pragma unroll
    for (int d = 1; d < 64; d <<= 1) { s1 += __shfl_xor(s1, d); s2 += __shfl_xor(s2, d); }
    float mean = s1 * (1.f / 512.f);
    float var = s2 * (1.f / 512.f) - mean * mean;
    float rs = rsqrtf(var + 1e-5f);
    float4 gv0 = ((const float4*)(gam + lane * 8))[0];
    float4 gv1 = ((const float4*)(gam + lane * 8))[1];
    float4 be0 = ((const float4*)(bet + lane * 8))[0];
    float4 be1 = ((const float4*)(bet + lane * 8))[1];
    float gg[8] = {gv0.x, gv0.y, gv0.z, gv0.w, gv1.x, gv1.y, gv1.z, gv1.w};
    float bb[8] = {be0.x, be0.y, be0.z, be0.w, be1.x, be1.y, be1.z, be1.w};
    float y[8];
#pragma unroll
    for (int j = 0; j < 8; ++j) y[j] = (x[j] - mean) * rs * gg[j] + bb[j];
    ((float4*)(yf + base))[0] = make_float4(y[0], y[1], y[2], y[3]);
    ((float4*)(yf + base))[1] = make_float4(y[4], y[5], y[6], y[7]);
    if (MODE <= 1) {
        ((ushort4*)(yb + base))[0] = make_ushort4(f2bf(y[0]), f2bf(y[1]), f2bf(y[2]), f2bf(y[3]));
        ((ushort4*)(yb + base))[1] = make_ushort4(f2bf(y[4]), f2bf(y[5]), f2bf(y[6]), f2bf(y[7]));
    }
    if (MODE == 0) {
        float4 p0 = ((const float4*)(pos + base))[0];
        float4 p1 = ((const float4*)(pos + base))[1];
        ((ushort4*)(qb + base))[0] = make_ushort4(f2bf(y[0] + p0.x), f2bf(y[1] + p0.y),
                                                  f2bf(y[2] + p0.z), f2bf(y[3] + p0.w));
        ((ushort4*)(qb + base))[1] = make_ushort4(f2bf(y[4] + p1.x), f2bf(y[5] + p1.y),
                                                  f2bf(y[6] + p1.z), f2bf(y[7] + p1.w));
    }
}

// ---------------------------------------------------------------- host
extern "C" void kernel_launch(void* const* d_in, const int* in_sizes, int n_in,
                              void* d_out, int out_size, void* d_ws, size_t ws_size,
                              hipStream_t stream) {
    (void)in_sizes; (void)n_in; (void)out_size; (void)ws_size;
    const float* tgt      = (const float*)d_in[0];
    const float* memory   = (const float*)d_in[1];
    const float* tgt_pos  = (const float*)d_in[2];
    const float* mem_pos  = (const float*)d_in[3];
    const int*   tgt_mask = (const int*)d_in[4];
    const int*   mem_mask = (const int*)d_in[5];
    const float* sa_b[4] = {(const float*)d_in[7], (const float*)d_in[9],
                            (const float*)d_in[11], (const float*)d_in[13]};
    const float* ca_b[4] = {(const float*)d_in[15], (const float*)d_in[17],
                            (const float*)d_in[19], (const float*)d_in[21]};
    const float* ln1_g = (const float*)d_in[22]; const float* ln1_b = (const float*)d_in[23];
    const float* ln2_g = (const float*)d_in[24]; const float* ln2_b = (const float*)d_in[25];
    const float* ln3_g = (const float*)d_in[26]; const float* ln3_b = (const float*)d_in[27];
    const float* mlp_b1 = (const float*)d_in[29];
    const float* mlp_b2 = (const float*)d_in[31];

    const size_t MiB = 1024 * 1024;
    char* ws = (char*)d_ws;           // total footprint: 81 MiB
    u16*  WT  = (u16*)(ws + 0);
    u32*  MBS = (u32*)(ws + 8 * MiB);
    u32*  MBC = (u32*)(ws + 8 * MiB + 512 * 1024);
    u16*  QIN = (u16*)(ws + 9 * MiB);
    u16*  TGTB= (u16*)(ws + 13 * MiB);
    u16*  MEMB= (u16*)(ws + 17 * MiB);
    u16*  MKB = (u16*)(ws + 21 * MiB);
    u16*  QM  = (u16*)(ws + 25 * MiB);
    u16*  KM  = (u16*)(ws + 29 * MiB);
    u16*  VM  = (u16*)(ws + 33 * MiB);
    u16*  VTM = (u16*)(ws + 37 * MiB);
    u16*  ATNB= (u16*)(ws + 41 * MiB);
    float* PROJ= (float*)(ws + 45 * MiB);
    float* X1F = (float*)(ws + 53 * MiB);
    u16*  X1B = (u16*)(ws + 61 * MiB);
    u16*  MQB = (u16*)(ws + 65 * MiB);
    float* X2F = (float*)(ws + 69 * MiB);
    u16*  X2B = (u16*)(ws + 77 * MiB);
    u16*  FFH = (u16*)(ws + 9 * MiB); // aliases QIN..MKB (dead by FFN phase)

    u16* wt[10];
    for (int z = 0; z < 8; ++z) wt[z] = WT + (size_t)z * 262144;
    wt[8] = WT + 2097152;
    wt[9] = WT + 3145728;

    // 1. weight transposes (z: sa q,k,v,o, ca q,k,v,o, w1, w2)
    W10 w10;
    w10.w[0] = (const float*)d_in[6];  w10.w[1] = (const float*)d_in[8];
    w10.w[2] = (const float*)d_in[10]; w10.w[3] = (const float*)d_in[12];
    w10.w[4] = (const float*)d_in[14]; w10.w[5] = (const float*)d_in[16];
    w10.w[6] = (const float*)d_in[18]; w10.w[7] = (const float*)d_in[20];
    w10.w[8] = (const float*)d_in[28]; w10.w[9] = (const float*)d_in[30];
    wtrans_kernel<<<dim3(1024, 10), dim3(32, 8), 0, stream>>>(w10, WT);

    // 2. mask packing
    packmask_kernel<<<32768, 256, 0, stream>>>(tgt_mask, mem_mask, MBS, MBC, 4 * 1024 * 1024);

    // 3. activation casts
    prep_kernel<<<2048, 256, 0, stream>>>(
        (const float4*)tgt, (const float4*)tgt_pos, (const float4*)memory, (const float4*)mem_pos,
        (ushort4*)QIN, (ushort4*)TGTB, (ushort4*)MEMB, (ushort4*)MKB, 524288);

    GemmArgs3 ga;
    // 4. SA q,k,v projections
    ga.s[0] = {QIN,  wt[0], sa_b[0], QM};
    ga.s[1] = {QIN,  wt[1], sa_b[1], KM};
    ga.s[2] = {TGTB, wt[2], sa_b[2], VM};
    gemm_kernel<0><<<dim3(8, 32, 3), 256, 0, stream>>>(ga, 4096, 512, 512);
    // 5. V transpose
    vtrans_kernel<<<dim3(32, 2, 32), dim3(32, 8), 0, stream>>>(VM, VTM, 1024);
    // 6. SA attention
    attn_kernel<<<dim3(16, 8, 4), 256, 0, stream>>>(QM, KM, VTM, MBS, ATNB, 1024, 1024);
    // 7. SA output projection (f32)
    ga.s[0] = {ATNB, wt[3], sa_b[3], PROJ}; ga.s[1] = ga.s[0]; ga.s[2] = ga.s[0];
    gemm_kernel<2><<<dim3(8, 32, 1), 256, 0, stream>>>(ga, 4096, 512, 512);
    // 8. LN1 (+ mq = x1 + tgt_pos)
    ln_kernel<0><<<1024, 256, 0, stream>>>(tgt, PROJ, ln1_g, ln1_b, tgt_pos, X1F, X1B, MQB);

    // 9. CA q,k,v projections
    ga.s[0] = {MQB,  wt[4], ca_b[0], QM};
    ga.s[1] = {MKB,  wt[5], ca_b[1], KM};
    ga.s[2] = {MEMB, wt[6], ca_b[2], VM};
    gemm_kernel<0><<<dim3(8, 32, 3), 256, 0, stream>>>(ga, 4096, 512, 512);
    // 10. V transpose
    vtrans_kernel<<<dim3(32, 2, 32), dim3(32, 8), 0, stream>>>(VM, VTM, 1024);
    // 11. CA attention
    attn_kernel<<<dim3(16, 8, 4), 256, 0, stream>>>(QM, KM, VTM, MBC, ATNB, 1024, 1024);
    // 12. CA output projection
    ga.s[0] = {ATNB, wt[7], ca_b[3], PROJ}; ga.s[1] = ga.s[0]; ga.s[2] = ga.s[0];
    gemm_kernel<2><<<dim3(8, 32, 1), 256, 0, stream>>>(ga, 4096, 512, 512);
    // 13. LN2
    ln_kernel<1><<<1024, 256, 0, stream>>>(X1F, PROJ, ln2_g, ln2_b, nullptr, X2F, X2B, nullptr);

    // 14. FFN1 (relu)
    ga.s[0] = {X2B, wt[8], mlp_b1, FFH}; ga.s[1] = ga.s[0]; ga.s[2] = ga.s[0];
    gemm_kernel<1><<<dim3(32, 32, 1), 256, 0, stream>>>(ga, 4096, 2048, 512);
    // 15. FFN2
    ga.s[0] = {FFH, wt[9], mlp_b2, PROJ}; ga.s[1] = ga.s[0]; ga.s[2] = ga.s[0];
    gemm_kernel<2><<<dim3(8, 32, 1), 256, 0, stream>>>(ga, 4096, 512, 2048);
    // 16. LN3 -> d_out
    ln_kernel<2><<<1024, 256, 0, stream>>>(X2F, PROJ, ln3_g, ln3_b, nullptr,
                                           (float*)d_out, nullptr, nullptr);
}

// Round 2
// 271.546 us; speedup vs baseline: 1.0913x; 1.0913x over previous
//
#include <hip/hip_runtime.h>
#include <stdint.h>

typedef unsigned int u32;
typedef unsigned long long u64;
typedef unsigned short u16;
typedef __attribute__((ext_vector_type(8))) __bf16 bf16x8;
typedef __attribute__((ext_vector_type(4))) float f32x4;

#define DEV __device__ __forceinline__

// f32 -> bf16 RTNE (finite values only; fine for this workload)
DEV u16 f2bf(float f) {
    u32 x = __builtin_bit_cast(u32, f);
    u32 r = (x + 0x7FFFu + ((x >> 16) & 1u)) >> 16;
    return (u16)r;
}

DEV bf16x8 ldg8(const u16* p) {
    return __builtin_bit_cast(bf16x8, *(const uint4*)p);
}

DEV u32 pk2(float a, float b) {
    return (u32)f2bf(a) | ((u32)f2bf(b) << 16);
}

DEV void g2l16(const u16* g, u16* l) {
    __builtin_amdgcn_global_load_lds(
        (const __attribute__((address_space(1))) u32*)g,
        (__attribute__((address_space(3))) u32*)l, 16, 0, 0);
}

DEV f32x4 mfma16(bf16x8 a, bf16x8 b, f32x4 c) {
    return __builtin_amdgcn_mfma_f32_16x16x32_bf16(a, b, c, 0, 0, 0);
}

// ---------------------------------------------------------------- mask pack
__global__ __launch_bounds__(256) void packmask_kernel(
    const int* __restrict__ m1, const int* __restrict__ m2,
    u32* __restrict__ o1, u32* __restrict__ o2, int n) {
    int i = blockIdx.x * 256 + threadIdx.x;
    bool first = i < n;
    int idx = first ? i : i - n;
    int v = first ? m1[idx] : m2[idx];
    u64 bal = __ballot(v != 0);
    if ((threadIdx.x & 31) == 0) {
        u32 w = (u32)(bal >> (threadIdx.x & 32));
        (first ? o1 : o2)[idx >> 5] = w;
    }
}

// ---------------------------------------------------------------- prep casts
__global__ __launch_bounds__(256) void prep_kernel(
    const float4* __restrict__ tgt, const float4* __restrict__ tpos,
    const float4* __restrict__ mem, const float4* __restrict__ mpos,
    ushort4* __restrict__ qin, ushort4* __restrict__ tgtb,
    ushort4* __restrict__ memb, ushort4* __restrict__ mkb, int n4) {
    int i = blockIdx.x * 256 + threadIdx.x;
    if (i >= n4) return;
    float4 t = tgt[i], p = tpos[i], m = mem[i], mp = mpos[i];
    qin[i]  = make_ushort4(f2bf(t.x + p.x), f2bf(t.y + p.y), f2bf(t.z + p.z), f2bf(t.w + p.w));
    tgtb[i] = make_ushort4(f2bf(t.x), f2bf(t.y), f2bf(t.z), f2bf(t.w));
    memb[i] = make_ushort4(f2bf(m.x), f2bf(m.y), f2bf(m.z), f2bf(m.w));
    mkb[i]  = make_ushort4(f2bf(m.x + mp.x), f2bf(m.y + mp.y), f2bf(m.z + mp.z), f2bf(m.w + mp.w));
}

// ---------------------------------------------------------------- weight transpose
struct W10 { const float* w[10]; };
__global__ __launch_bounds__(256) void wtrans_kernel(W10 ws, u16* wtbase) {
    int z = blockIdx.y;
    int Kd = (z == 9) ? 2048 : 512;
    int Nd = (z == 8) ? 2048 : 512;
    size_t off = (z < 8) ? (size_t)z * 262144
                         : (z == 8 ? (size_t)2097152 : (size_t)3145728);
    u16* out = wtbase + off;
    int nx = Nd / 32;
    int txile = blockIdx.x % nx, tyile = blockIdx.x / nx;
    if (tyile >= Kd / 32) return;
    const float* w = ws.w[z];
    __shared__ float t[32][33];
    int tx = threadIdx.x, ty = threadIdx.y;
#pragma unroll
    for (int j = 0; j < 4; ++j)
        t[ty + j * 8][tx] = w[(size_t)(tyile * 32 + ty + j * 8) * Nd + txile * 32 + tx];
    __syncthreads();
#pragma unroll
    for (int j = 0; j < 4; ++j)
        out[(size_t)(txile * 32 + ty + j * 8) * Kd + tyile * 32 + tx] = f2bf(t[tx][ty + j * 8]);
}

// ---------------------------------------------------------------- V transpose
__global__ __launch_bounds__(256) void vtrans_kernel(
    const u16* __restrict__ V, u16* __restrict__ VT, int L) {
    int z = blockIdx.z, b = z >> 3, h = z & 7;
    int s0 = blockIdx.x * 32, d0 = blockIdx.y * 32;
    __shared__ u16 t[32][33];
    int tx = threadIdx.x, ty = threadIdx.y;
#pragma unroll
    for (int j = 0; j < 4; ++j)
        t[ty + j * 8][tx] = V[(size_t)(b * L + s0 + ty + j * 8) * 512 + h * 64 + d0 + tx];
    __syncthreads();
#pragma unroll
    for (int j = 0; j < 4; ++j)
        VT[((size_t)z * 64 + d0 + ty + j * 8) * L + s0 + tx] = t[tx][ty + j * 8];
}

// ---------------------------------------------------------------- GEMM
// C[M][N] = (A[M][K](bf16) @ W^T[N][K](bf16) + bias) * oscale
// EPI: 0 bf16, 1 bf16+relu, 2 f32
struct GemmSet { const u16* A; const u16* W; const float* bias; void* out; float oscale; };
struct GemmArgs3 { GemmSet s[3]; };

template <int EPI, int BM>
__global__ __launch_bounds__(256) void gemm_kernel(GemmArgs3 args, int M, int N, int Kd) {
    constexpr int MF = BM / 32;          // m-fragments per wave
    const GemmSet gs = args.s[blockIdx.z];
    const u16* __restrict__ A = gs.A;
    const u16* __restrict__ W = gs.W;
    const int t = threadIdx.x;
    const int lane = t & 63, wave = t >> 6;
    const int g = lane >> 4, r16 = lane & 15;
    const int wm = wave >> 1, wn = wave & 1;
    const int m0 = blockIdx.y * BM, n0 = blockIdx.x * 64;

    __shared__ __align__(16) u16 As[BM * 64];
    __shared__ __align__(16) u16 Bs[64 * 64];

    f32x4 acc[MF][2];
#pragma unroll
    for (int m = 0; m < MF; ++m)
#pragma unroll
        for (int n = 0; n < 2; ++n) acc[m][n] = f32x4{0.f, 0.f, 0.f, 0.f};

    for (int kk = 0; kk < Kd; kk += 64) {
        __syncthreads();
#pragma unroll
        for (int i = 0; i < BM / 32; ++i) {
            int cid = t + i * 256, row = cid >> 3, c = cid & 7;
            g2l16(A + (size_t)(m0 + row) * Kd + kk + ((c ^ (row & 7)) << 3), &As[cid << 3]);
        }
#pragma unroll
        for (int i = 0; i < 2; ++i) {
            int cid = t + i * 256, row = cid >> 3, c = cid & 7;
            g2l16(W + (size_t)(n0 + row) * Kd + kk + ((c ^ (row & 7)) << 3), &Bs[cid << 3]);
        }
        __syncthreads();
#pragma unroll
        for (int ks = 0; ks < 2; ++ks) {
            bf16x8 af[MF], bfr[2];
#pragma unroll
            for (int m = 0; m < MF; ++m) {
                int row = wm * (MF * 16) + m * 16 + r16;
                af[m] = *(const bf16x8*)&As[(row << 6) + (((ks * 4 + g) ^ (row & 7)) << 3)];
            }
#pragma unroll
            for (int n = 0; n < 2; ++n) {
                int row = wn * 32 + n * 16 + r16;
                bfr[n] = *(const bf16x8*)&Bs[(row << 6) + (((ks * 4 + g) ^ (row & 7)) << 3)];
            }
#pragma unroll
            for (int m = 0; m < MF; ++m)
#pragma unroll
                for (int n = 0; n < 2; ++n)
                    acc[m][n] = mfma16(af[m], bfr[n], acc[m][n]);
        }
    }
#pragma unroll
    for (int m = 0; m < MF; ++m) {
        int row0 = m0 + wm * (MF * 16) + m * 16 + g * 4;
#pragma unroll
        for (int n = 0; n < 2; ++n) {
            int col = n0 + wn * 32 + n * 16 + r16;
            float bv = gs.bias[col];
#pragma unroll
            for (int r = 0; r < 4; ++r) {
                float v = (acc[m][n][r] + bv) * gs.oscale;
                if (EPI == 1) v = fmaxf(v, 0.f);
                size_t idx = (size_t)(row0 + r) * N + col;
                if (EPI == 2) ((float*)gs.out)[idx] = v;
                else ((u16*)gs.out)[idx] = f2bf(v);
            }
        }
    }
}

// ---------------------------------------------------------------- attention
// Q (pre-scaled by 1/8), K bf16 [B*L][512]; VT bf16 [B][8][64][Lk]; mb bitmask
// scores masked -> 1e-9 ; softmax ; PV.  One wave = 16 q rows; 64 k per iter.
__global__ __launch_bounds__(256) void attn_kernel(
    const u16* __restrict__ Q, const u16* __restrict__ K,
    const u16* __restrict__ VT, const u32* __restrict__ mb,
    u16* __restrict__ O, int Lq, int Lk) {
    const int t = threadIdx.x, lane = t & 63, wave = t >> 6;
    const int g = lane >> 4, r16 = lane & 15;
    const int h = blockIdx.y, b = blockIdx.z;
    const int q0 = blockIdx.x * 64 + wave * 16;
    const int D = 512;
    __shared__ __align__(16) u16 Pl[4][16][72];  // row stride 144B

    const size_t qrow = (size_t)b * Lq + q0 + r16;
    const u16* qp = Q + qrow * D + h * 64 + g * 8;
    bf16x8 qb0 = ldg8(qp);
    bf16x8 qb1 = ldg8(qp + 32);
    const u32* mrow = mb + qrow * (Lk >> 5);

    f32x4 acc[4];
#pragma unroll
    for (int dt = 0; dt < 4; ++dt) acc[dt] = f32x4{0.f, 0.f, 0.f, 0.f};
    float mrun = -INFINITY, lrun = 0.f;
    const f32x4 zf = {0.f, 0.f, 0.f, 0.f};

    const u16* kb_base = K + (size_t)b * Lk * D + h * 64 + g * 8;
    const u16* vt_base = VT + ((size_t)(b * 8 + h) * 64 + r16) * Lk + g * 8;

    // preload K chunk 0
    bf16x8 ka[8];
#pragma unroll
    for (int j = 0; j < 4; ++j) {
        const u16* kp = kb_base + (size_t)(16 * j + r16) * D;
        ka[2 * j] = ldg8(kp);
        ka[2 * j + 1] = ldg8(kp + 32);
    }

    for (int kc = 0; kc < Lk; kc += 64) {
        // QK^T (swapped: A=K rows, B=Q cols)
        f32x4 s[4];
#pragma unroll
        for (int j = 0; j < 4; ++j) {
            s[j] = mfma16(ka[2 * j], qb0, zf);
            s[j] = mfma16(ka[2 * j + 1], qb1, s[j]);
        }
        // prefetch next K chunk (overlaps softmax)
        if (kc + 64 < Lk) {
#pragma unroll
            for (int j = 0; j < 4; ++j) {
                const u16* kp = kb_base + (size_t)(kc + 64 + 16 * j + r16) * D;
                ka[2 * j] = ldg8(kp);
                ka[2 * j + 1] = ldg8(kp + 32);
            }
        }
        // V loads for this chunk (overlap softmax)
        bf16x8 vf[4][2];
#pragma unroll
        for (int dt = 0; dt < 4; ++dt)
#pragma unroll
            for (int ks = 0; ks < 2; ++ks)
                vf[dt][ks] = ldg8(vt_base + (size_t)dt * 16 * Lk + kc + ks * 32);

        // mask -> sv[16]; s[j][r] = S[kc+16j+g*4+r][q=r16]
        u32 mw0 = mrow[kc >> 5], mw1 = mrow[(kc >> 5) + 1];
        float sv[16];
#pragma unroll
        for (int j = 0; j < 4; ++j) {
            u32 w = (j < 2) ? mw0 : mw1;
            int base = (16 * j) & 31;
#pragma unroll
            for (int r = 0; r < 4; ++r) {
                int bit = base + g * 4 + r;
                sv[4 * j + r] = ((w >> bit) & 1) ? s[j][r] : 1e-9f;
            }
        }
        // row max (across 16 local + lanes with same r16)
        float tm = fmaxf(fmaxf(fmaxf(sv[0], sv[1]), fmaxf(sv[2], sv[3])),
                         fmaxf(fmaxf(sv[4], sv[5]), fmaxf(sv[6], sv[7])));
        float tm2 = fmaxf(fmaxf(fmaxf(sv[8], sv[9]), fmaxf(sv[10], sv[11])),
                          fmaxf(fmaxf(sv[12], sv[13]), fmaxf(sv[14], sv[15])));
        tm = fmaxf(tm, tm2);
        tm = fmaxf(tm, __shfl_xor(tm, 16));
        tm = fmaxf(tm, __shfl_xor(tm, 32));
        // defer-max: only rescale when max grew by > 8
        if (!__all(tm <= mrun + 8.f)) {
            float mn = fmaxf(mrun, tm);
            float alpha = __expf(mrun - mn);
            mrun = mn;
            lrun *= alpha;
#pragma unroll
            for (int r = 0; r < 4; ++r) {
                float ar = __shfl(alpha, g * 4 + r);
#pragma unroll
                for (int dt = 0; dt < 4; ++dt) acc[dt][r] *= ar;
            }
        }
        float ts = 0.f;
#pragma unroll
        for (int jj = 0; jj < 16; ++jj) { sv[jj] = __expf(sv[jj] - mrun); ts += sv[jj]; }
        ts += __shfl_xor(ts, 16);
        ts += __shfl_xor(ts, 32);
        lrun += ts;
        // P -> LDS (redistribute to A-fragment layout)
#pragma unroll
        for (int j = 0; j < 4; ++j) {
            uint2 u;
            u.x = pk2(sv[4 * j], sv[4 * j + 1]);
            u.y = pk2(sv[4 * j + 2], sv[4 * j + 3]);
            *(uint2*)&Pl[wave][r16][16 * j + g * 4] = u;
        }
        bf16x8 pf0 = *(const bf16x8*)&Pl[wave][r16][g * 8];
        bf16x8 pf1 = *(const bf16x8*)&Pl[wave][r16][32 + g * 8];
#pragma unroll
        for (int dt = 0; dt < 4; ++dt) {
            acc[dt] = mfma16(pf0, vf[dt][0], acc[dt]);
            acc[dt] = mfma16(pf1, vf[dt][1], acc[dt]);
        }
    }
    float li[4];
#pragma unroll
    for (int r = 0; r < 4; ++r) li[r] = 1.f / __shfl(lrun, g * 4 + r);
    const size_t obase = ((size_t)b * Lq + q0) * D + h * 64;
#pragma unroll
    for (int dt = 0; dt < 4; ++dt)
#pragma unroll
        for (int r = 0; r < 4; ++r)
            O[obase + (size_t)(g * 4 + r) * D + dt * 16 + r16] = f2bf(acc[dt][r] * li[r]);
}

// ---------------------------------------------------------------- LayerNorm
template <int MODE>
__global__ __launch_bounds__(256) void ln_kernel(
    const float* __restrict__ a, const float* __restrict__ bsrc,
    const float* __restrict__ gam, const float* __restrict__ bet,
    const float* __restrict__ pos,
    float* __restrict__ yf, u16* __restrict__ yb, u16* __restrict__ qb) {
    const int lane = threadIdx.x & 63;
    const int row = blockIdx.x * 4 + (threadIdx.x >> 6);
    const size_t base = (size_t)row * 512 + lane * 8;
    float4 av0 = ((const float4*)(a + base))[0];
    float4 av1 = ((const float4*)(a + base))[1];
    float4 bv0 = ((const float4*)(bsrc + base))[0];
    float4 bv1 = ((const float4*)(bsrc + base))[1];
    float x[8] = {av0.x + bv0.x, av0.y + bv0.y, av0.z + bv0.z, av0.w + bv0.w,
                  av1.x + bv1.x, av1.y + bv1.y, av1.z + bv1.z, av1.w + bv1.w};
    float s1 = 0.f, s2 = 0.f;
#pragma unroll
    for (int j = 0; j < 8; ++j) { s1 += x[j]; s2 += x[j] * x[j]; }
#pragma unroll
    for (int d = 1; d < 64; d <<= 1) { s1 += __shfl_xor(s1, d); s2 += __shfl_xor(s2, d); }
    float mean = s1 * (1.f / 512.f);
    float var = s2 * (1.f / 512.f) - mean * mean;
    float rs = rsqrtf(var + 1e-5f);
    float4 gv0 = ((const float4*)(gam + lane * 8))[0];
    float4 gv1 = ((const float4*)(gam + lane * 8))[1];
    float4 be0 = ((const float4*)(bet + lane * 8))[0];
    float4 be1 = ((const float4*)(bet + lane * 8))[1];
    float gg[8] = {gv0.x, gv0.y, gv0.z, gv0.w, gv1.x, gv1.y, gv1.z, gv1.w};
    float bb[8] = {be0.x, be0.y, be0.z, be0.w, be1.x, be1.y, be1.z, be1.w};
    float y[8];
#pragma unroll
    for (int j = 0; j < 8; ++j) y[j] = (x[j] - mean) * rs * gg[j] + bb[j];
    ((float4*)(yf + base))[0] = make_float4(y[0], y[1], y[2], y[3]);
    ((float4*)(yf + base))[1] = make_float4(y[4], y[5], y[6], y[7]);
    if (MODE <= 1) {
        ((ushort4*)(yb + base))[0] = make_ushort4(f2bf(y[0]), f2bf(y[1]), f2bf(y[2]), f2bf(y[3]));
        ((ushort4*)(yb + base))[1] = make_ushort4(f2bf(y[4]), f2bf(y[5]), f2bf(y[6]), f2bf(y[7]));
    }
    if (MODE == 0) {
        float4 p0 = ((const float4*)(pos + base))[0];
        float4 p1 = ((const float4*)(pos + base))[1];
        ((ushort4*)(qb + base))[0] = make_ushort4(f2bf(y[0] + p0.x), f2bf(y[1] + p0.y),
                                                  f2bf(y[2] + p0.z), f2bf(y[3] + p0.w));
        ((ushort4*)(qb + base))[1] = make_ushort4(f2bf(y[4] + p1.x), f2bf(y[5] + p1.y),
                                                  f2bf(y[6] + p1.z), f2bf(y[7] + p1.w));
    }
}

// ---------------------------------------------------------------- host
extern "C" void kernel_launch(void* const* d_in, const int* in_sizes, int n_in,
                              void* d_out, int out_size, void* d_ws, size_t ws_size,
                              hipStream_t stream) {
    (void)in_sizes; (void)n_in; (void)out_size; (void)ws_size;
    const float* tgt      = (const float*)d_in[0];
    const float* memory   = (const float*)d_in[1];
    const float* tgt_pos  = (const float*)d_in[2];
    const float* mem_pos  = (const float*)d_in[3];
    const int*   tgt_mask = (const int*)d_in[4];
    const int*   mem_mask = (const int*)d_in[5];
    const float* sa_b[4] = {(const float*)d_in[7], (const float*)d_in[9],
                            (const float*)d_in[11], (const float*)d_in[13]};
    const float* ca_b[4] = {(const float*)d_in[15], (const float*)d_in[17],
                            (const float*)d_in[19], (const float*)d_in[21]};
    const float* ln1_g = (const float*)d_in[22]; const float* ln1_b = (const float*)d_in[23];
    const float* ln2_g = (const float*)d_in[24]; const float* ln2_b = (const float*)d_in[25];
    const float* ln3_g = (const float*)d_in[26]; const float* ln3_b = (const float*)d_in[27];
    const float* mlp_b1 = (const float*)d_in[29];
    const float* mlp_b2 = (const float*)d_in[31];

    const size_t MiB = 1024 * 1024;
    char* ws = (char*)d_ws;
    u16*  WT  = (u16*)(ws + 0);
    u32*  MBS = (u32*)(ws + 8 * MiB);
    u32*  MBC = (u32*)(ws + 8 * MiB + 512 * 1024);
    u16*  QIN = (u16*)(ws + 9 * MiB);
    u16*  TGTB= (u16*)(ws + 13 * MiB);
    u16*  MEMB= (u16*)(ws + 17 * MiB);
    u16*  MKB = (u16*)(ws + 21 * MiB);
    u16*  QM  = (u16*)(ws + 25 * MiB);
    u16*  KM  = (u16*)(ws + 29 * MiB);
    u16*  VM  = (u16*)(ws + 33 * MiB);
    u16*  VTM = (u16*)(ws + 37 * MiB);
    u16*  ATNB= (u16*)(ws + 41 * MiB);
    float* PROJ= (float*)(ws + 45 * MiB);
    float* X1F = (float*)(ws + 53 * MiB);
    u16*  X1B = (u16*)(ws + 61 * MiB);
    u16*  MQB = (u16*)(ws + 65 * MiB);
    float* X2F = (float*)(ws + 69 * MiB);
    u16*  X2B = (u16*)(ws + 77 * MiB);
    u16*  FFH = (u16*)(ws + 9 * MiB); // aliases QIN..MKB (dead by FFN phase)

    u16* wt[10];
    for (int z = 0; z < 8; ++z) wt[z] = WT + (size_t)z * 262144;
    wt[8] = WT + 2097152;
    wt[9] = WT + 3145728;

    W10 w10;
    w10.w[0] = (const float*)d_in[6];  w10.w[1] = (const float*)d_in[8];
    w10.w[2] = (const float*)d_in[10]; w10.w[3] = (const float*)d_in[12];
    w10.w[4] = (const float*)d_in[14]; w10.w[5] = (const float*)d_in[16];
    w10.w[6] = (const float*)d_in[18]; w10.w[7] = (const float*)d_in[20];
    w10.w[8] = (const float*)d_in[28]; w10.w[9] = (const float*)d_in[30];
    wtrans_kernel<<<dim3(1024, 10), dim3(32, 8), 0, stream>>>(w10, WT);

    packmask_kernel<<<32768, 256, 0, stream>>>(tgt_mask, mem_mask, MBS, MBC, 4 * 1024 * 1024);

    prep_kernel<<<2048, 256, 0, stream>>>(
        (const float4*)tgt, (const float4*)tgt_pos, (const float4*)memory, (const float4*)mem_pos,
        (ushort4*)QIN, (ushort4*)TGTB, (ushort4*)MEMB, (ushort4*)MKB, 524288);

    GemmArgs3 ga;
    // SA q,k,v projections (Q pre-scaled by 1/sqrt(dk)=0.125)
    ga.s[0] = {QIN,  wt[0], sa_b[0], QM, 0.125f};
    ga.s[1] = {QIN,  wt[1], sa_b[1], KM, 1.f};
    ga.s[2] = {TGTB, wt[2], sa_b[2], VM, 1.f};
    gemm_kernel<0, 128><<<dim3(8, 32, 3), 256, 0, stream>>>(ga, 4096, 512, 512);
    vtrans_kernel<<<dim3(32, 2, 32), dim3(32, 8), 0, stream>>>(VM, VTM, 1024);
    attn_kernel<<<dim3(16, 8, 4), 256, 0, stream>>>(QM, KM, VTM, MBS, ATNB, 1024, 1024);
    // SA output projection (f32) — 64-tile for occupancy
    ga.s[0] = {ATNB, wt[3], sa_b[3], PROJ, 1.f}; ga.s[1] = ga.s[0]; ga.s[2] = ga.s[0];
    gemm_kernel<2, 64><<<dim3(8, 64, 1), 256, 0, stream>>>(ga, 4096, 512, 512);
    ln_kernel<0><<<1024, 256, 0, stream>>>(tgt, PROJ, ln1_g, ln1_b, tgt_pos, X1F, X1B, MQB);

    // CA q,k,v projections
    ga.s[0] = {MQB,  wt[4], ca_b[0], QM, 0.125f};
    ga.s[1] = {MKB,  wt[5], ca_b[1], KM, 1.f};
    ga.s[2] = {MEMB, wt[6], ca_b[2], VM, 1.f};
    gemm_kernel<0, 128><<<dim3(8, 32, 3), 256, 0, stream>>>(ga, 4096, 512, 512);
    vtrans_kernel<<<dim3(32, 2, 32), dim3(32, 8), 0, stream>>>(VM, VTM, 1024);
    attn_kernel<<<dim3(16, 8, 4), 256, 0, stream>>>(QM, KM, VTM, MBC, ATNB, 1024, 1024);
    ga.s[0] = {ATNB, wt[7], ca_b[3], PROJ, 1.f}; ga.s[1] = ga.s[0]; ga.s[2] = ga.s[0];
    gemm_kernel<2, 64><<<dim3(8, 64, 1), 256, 0, stream>>>(ga, 4096, 512, 512);
    ln_kernel<1><<<1024, 256, 0, stream>>>(X1F, PROJ, ln2_g, ln2_b, nullptr, X2F, X2B, nullptr);

    // FFN
    ga.s[0] = {X2B, wt[8], mlp_b1, FFH, 1.f}; ga.s[1] = ga.s[0]; ga.s[2] = ga.s[0];
    gemm_kernel<1, 128><<<dim3(32, 32, 1), 256, 0, stream>>>(ga, 4096, 2048, 512);
    ga.s[0] = {FFH, wt[9], mlp_b2, PROJ, 1.f}; ga.s[1] = ga.s[0]; ga.s[2] = ga.s[0];
    gemm_kernel<2, 64><<<dim3(8, 64, 1), 256, 0, stream>>>(ga, 4096, 512, 2048);
    ln_kernel<2><<<1024, 256, 0, stream>>>(X2F, PROJ, ln3_g, ln3_b, nullptr,
                                           (float*)d_out, nullptr, nullptr);
}

// Round 3
// 220.265 us; speedup vs baseline: 1.3454x; 1.2328x over previous
//
#include <hip/hip_runtime.h>
#include <stdint.h>

typedef unsigned int u32;
typedef unsigned long long u64;
typedef unsigned short u16;
typedef __attribute__((ext_vector_type(8))) __bf16 bf16x8;
typedef __attribute__((ext_vector_type(4))) float f32x4;

#define DEV __device__ __forceinline__

DEV u16 f2bf(float f) {
    u32 x = __builtin_bit_cast(u32, f);
    u32 r = (x + 0x7FFFu + ((x >> 16) & 1u)) >> 16;
    return (u16)r;
}

DEV bf16x8 ldg8(const u16* p) {
    return __builtin_bit_cast(bf16x8, *(const uint4*)p);
}

DEV u32 pk2(float a, float b) {
    return (u32)f2bf(a) | ((u32)f2bf(b) << 16);
}

DEV void g2l16(const u16* g, u16* l) {
    __builtin_amdgcn_global_load_lds(
        (const __attribute__((address_space(1))) u32*)g,
        (__attribute__((address_space(3))) u32*)l, 16, 0, 0);
}

DEV f32x4 mfma16(bf16x8 a, bf16x8 b, f32x4 c) {
    return __builtin_amdgcn_mfma_f32_16x16x32_bf16(a, b, c, 0, 0, 0);
}

// ---------------------------------------------------------------- mask pack
__global__ __launch_bounds__(256) void packmask_kernel(
    const int* __restrict__ m1, const int* __restrict__ m2,
    u32* __restrict__ o1, u32* __restrict__ o2, int n) {
    int i = blockIdx.x * 256 + threadIdx.x;
    bool first = i < n;
    int idx = first ? i : i - n;
    int v = first ? m1[idx] : m2[idx];
    u64 bal = __ballot(v != 0);
    if ((threadIdx.x & 31) == 0) {
        u32 w = (u32)(bal >> (threadIdx.x & 32));
        (first ? o1 : o2)[idx >> 5] = w;
    }
}

// ---------------------------------------------------------------- prep casts
__global__ __launch_bounds__(256) void prep_kernel(
    const float4* __restrict__ tgt, const float4* __restrict__ tpos,
    const float4* __restrict__ mem, const float4* __restrict__ mpos,
    ushort4* __restrict__ qin, ushort4* __restrict__ tgtb,
    ushort4* __restrict__ memb, ushort4* __restrict__ mkb, int n4) {
    int i = blockIdx.x * 256 + threadIdx.x;
    if (i >= n4) return;
    float4 t = tgt[i], p = tpos[i], m = mem[i], mp = mpos[i];
    qin[i]  = make_ushort4(f2bf(t.x + p.x), f2bf(t.y + p.y), f2bf(t.z + p.z), f2bf(t.w + p.w));
    tgtb[i] = make_ushort4(f2bf(t.x), f2bf(t.y), f2bf(t.z), f2bf(t.w));
    memb[i] = make_ushort4(f2bf(m.x), f2bf(m.y), f2bf(m.z), f2bf(m.w));
    mkb[i]  = make_ushort4(f2bf(m.x + mp.x), f2bf(m.y + mp.y), f2bf(m.z + mp.z), f2bf(m.w + mp.w));
}

// ---------------------------------------------------------------- weight transpose
struct W10 { const float* w[10]; };
__global__ __launch_bounds__(256) void wtrans_kernel(W10 ws, u16* wtbase) {
    int z = blockIdx.y;
    int Kd = (z == 9) ? 2048 : 512;
    int Nd = (z == 8) ? 2048 : 512;
    size_t off = (z < 8) ? (size_t)z * 262144
                         : (z == 8 ? (size_t)2097152 : (size_t)3145728);
    u16* out = wtbase + off;
    int nx = Nd / 32;
    int txile = blockIdx.x % nx, tyile = blockIdx.x / nx;
    if (tyile >= Kd / 32) return;
    const float* w = ws.w[z];
    __shared__ float t[32][33];
    int tx = threadIdx.x, ty = threadIdx.y;
#pragma unroll
    for (int j = 0; j < 4; ++j)
        t[ty + j * 8][tx] = w[(size_t)(tyile * 32 + ty + j * 8) * Nd + txile * 32 + tx];
    __syncthreads();
#pragma unroll
    for (int j = 0; j < 4; ++j)
        out[(size_t)(txile * 32 + ty + j * 8) * Kd + tyile * 32 + tx] = f2bf(t[tx][ty + j * 8]);
}

// ---------------------------------------------------------------- V transpose
__global__ __launch_bounds__(256) void vtrans_kernel(
    const u16* __restrict__ V, u16* __restrict__ VT, int L) {
    int z = blockIdx.z, b = z >> 3, h = z & 7;
    int s0 = blockIdx.x * 32, d0 = blockIdx.y * 32;
    __shared__ u16 t[32][33];
    int tx = threadIdx.x, ty = threadIdx.y;
#pragma unroll
    for (int j = 0; j < 4; ++j)
        t[ty + j * 8][tx] = V[(size_t)(b * L + s0 + ty + j * 8) * 512 + h * 64 + d0 + tx];
    __syncthreads();
#pragma unroll
    for (int j = 0; j < 4; ++j)
        VT[((size_t)z * 64 + d0 + ty + j * 8) * L + s0 + tx] = t[tx][ty + j * 8];
}

// ---------------------------------------------------------------- GEMM
struct GemmSet { const u16* A; const u16* W; const float* bias; void* out; float oscale; };
struct GemmArgs3 { GemmSet s[3]; };

template <int EPI, int BM>
__global__ __launch_bounds__(256) void gemm_kernel(GemmArgs3 args, int M, int N, int Kd) {
    constexpr int MF = BM / 32;
    const GemmSet gs = args.s[blockIdx.z];
    const u16* __restrict__ A = gs.A;
    const u16* __restrict__ W = gs.W;
    const int t = threadIdx.x;
    const int lane = t & 63;
    const int g = lane >> 4, r16 = lane & 15;
    const int wave = t >> 6;
    const int wm = wave >> 1, wn = wave & 1;
    const int m0 = blockIdx.y * BM, n0 = blockIdx.x * 64;

    __shared__ __align__(16) u16 As[BM * 64];
    __shared__ __align__(16) u16 Bs[64 * 64];

    f32x4 acc[MF][2];
#pragma unroll
    for (int m = 0; m < MF; ++m)
#pragma unroll
        for (int n = 0; n < 2; ++n) acc[m][n] = f32x4{0.f, 0.f, 0.f, 0.f};

    for (int kk = 0; kk < Kd; kk += 64) {
        __syncthreads();
#pragma unroll
        for (int i = 0; i < BM / 32; ++i) {
            int cid = t + i * 256, row = cid >> 3, c = cid & 7;
            g2l16(A + (size_t)(m0 + row) * Kd + kk + ((c ^ (row & 7)) << 3), &As[cid << 3]);
        }
#pragma unroll
        for (int i = 0; i < 2; ++i) {
            int cid = t + i * 256, row = cid >> 3, c = cid & 7;
            g2l16(W + (size_t)(n0 + row) * Kd + kk + ((c ^ (row & 7)) << 3), &Bs[cid << 3]);
        }
        __syncthreads();
#pragma unroll
        for (int ks = 0; ks < 2; ++ks) {
            bf16x8 af[MF], bfr[2];
#pragma unroll
            for (int m = 0; m < MF; ++m) {
                int row = wm * (MF * 16) + m * 16 + r16;
                af[m] = *(const bf16x8*)&As[(row << 6) + (((ks * 4 + g) ^ (row & 7)) << 3)];
            }
#pragma unroll
            for (int n = 0; n < 2; ++n) {
                int row = wn * 32 + n * 16 + r16;
                bfr[n] = *(const bf16x8*)&Bs[(row << 6) + (((ks * 4 + g) ^ (row & 7)) << 3)];
            }
#pragma unroll
            for (int m = 0; m < MF; ++m)
#pragma unroll
                for (int n = 0; n < 2; ++n)
                    acc[m][n] = mfma16(af[m], bfr[n], acc[m][n]);
        }
    }
#pragma unroll
    for (int m = 0; m < MF; ++m) {
        int row0 = m0 + wm * (MF * 16) + m * 16 + g * 4;
#pragma unroll
        for (int n = 0; n < 2; ++n) {
            int col = n0 + wn * 32 + n * 16 + r16;
            float bv = gs.bias[col];
#pragma unroll
            for (int r = 0; r < 4; ++r) {
                float v = (acc[m][n][r] + bv) * gs.oscale;
                if (EPI == 1) v = fmaxf(v, 0.f);
                size_t idx = (size_t)(row0 + r) * N + col;
                if (EPI == 2) ((float*)gs.out)[idx] = v;
                else ((u16*)gs.out)[idx] = f2bf(v);
            }
        }
    }
}

// ---------------------------------------------------------------- attention (partial over Lk/2)
// Q (pre-scaled), K bf16 [B*L][512]; VT bf16 [B*8][64][Lk]; mb bitmask.
// Each block: 64 q rows (4 waves x 16), one (b,h), Lk partition of 512.
// Output: unnormalized f32 acc + (m,l) per row -> combine kernel.
__global__ __launch_bounds__(256) void attn_part_kernel(
    const u16* __restrict__ Q, const u16* __restrict__ K,
    const u16* __restrict__ VT, const u32* __restrict__ mb,
    float* __restrict__ O0, float* __restrict__ O1, float2* __restrict__ ML,
    int Lq, int Lk) {
    const int t = threadIdx.x, lane = t & 63, wave = t >> 6;
    const int g = lane >> 4, r16 = lane & 15;
    const int h = blockIdx.y;
    const int b = blockIdx.z >> 1, p = blockIdx.z & 1;
    const int bh = b * 8 + h;
    const int q0 = blockIdx.x * 64 + wave * 16;
    const int kc0 = p * (Lk >> 1);
    const int NCH = (Lk >> 1) >> 5;   // 16 chunks of 32 keys

    __shared__ __align__(16) u16 Ks[2][32][64];   // [k][d], source-swizzled
    __shared__ __align__(16) u16 Vs[2][64][32];   // [d][k], linear
    __shared__ __align__(16) u16 Pl[4][16][40];

    const size_t qrow = (size_t)b * Lq + q0 + r16;
    const u16* qp = Q + qrow * 512 + h * 64 + g * 8;
    bf16x8 qb0 = ldg8(qp), qb1 = ldg8(qp + 32);
    const u32* mrow = mb + qrow * (Lk >> 5);

    // staging source addresses (this thread's 16B slot)
    const int srow = t >> 3, sc = t & 7;
    const u16* kg = K + (size_t)b * Lk * 512 + h * 64 + (size_t)srow * 512 + ((sc ^ (srow & 7)) << 3);
    const int vd = t >> 2, vc = t & 3;
    const u16* vg = VT + ((size_t)bh * 64 + vd) * Lk + (vc << 3);
    u16* const ks_base = &Ks[0][0][0];
    u16* const vs_base = &Vs[0][0][0];

    f32x4 acc[4];
#pragma unroll
    for (int dt = 0; dt < 4; ++dt) acc[dt] = f32x4{0.f, 0.f, 0.f, 0.f};
    float mrun = -INFINITY, lrun = 0.f;
    const f32x4 zf = {0.f, 0.f, 0.f, 0.f};

    // stage chunk 0
    g2l16(kg + (size_t)kc0 * 512, ks_base + t * 8);
    g2l16(vg + kc0, vs_base + t * 8);
    __syncthreads();

    for (int c = 0; c < NCH; ++c) {
        const int buf = c & 1, nbuf = buf ^ 1;
        const int kc = kc0 + c * 32;
        if (c + 1 < NCH) {
            g2l16(kg + (size_t)(kc + 32) * 512, ks_base + nbuf * 2048 + t * 8);
            g2l16(vg + kc + 32, vs_base + nbuf * 2048 + t * 8);
        }
        const u16* kb = ks_base + buf * 2048;
        const u16* vb = vs_base + buf * 2048;
        const int r1 = 16 + r16;
        bf16x8 k00 = *(const bf16x8*)(kb + r16 * 64 + ((g ^ (r16 & 7)) << 3));
        bf16x8 k01 = *(const bf16x8*)(kb + r16 * 64 + (((4 + g) ^ (r16 & 7)) << 3));
        bf16x8 k10 = *(const bf16x8*)(kb + r1 * 64 + ((g ^ (r1 & 7)) << 3));
        bf16x8 k11 = *(const bf16x8*)(kb + r1 * 64 + (((4 + g) ^ (r1 & 7)) << 3));
        f32x4 s0 = mfma16(k00, qb0, zf); s0 = mfma16(k01, qb1, s0);
        f32x4 s1 = mfma16(k10, qb0, zf); s1 = mfma16(k11, qb1, s1);

        u32 mw = mrow[kc >> 5];
        float sv[8];
#pragma unroll
        for (int r = 0; r < 4; ++r) {
            sv[r]     = ((mw >> (g * 4 + r)) & 1) ? s0[r] : 1e-9f;
            sv[4 + r] = ((mw >> (16 + g * 4 + r)) & 1) ? s1[r] : 1e-9f;
        }
        float tm = fmaxf(fmaxf(fmaxf(sv[0], sv[1]), fmaxf(sv[2], sv[3])),
                         fmaxf(fmaxf(sv[4], sv[5]), fmaxf(sv[6], sv[7])));
        tm = fmaxf(tm, __shfl_xor(tm, 16));
        tm = fmaxf(tm, __shfl_xor(tm, 32));
        if (!__all(tm <= mrun + 8.f)) {
            float mn = fmaxf(mrun, tm);
            float alpha = __expf(mrun - mn);
            mrun = mn;
            lrun *= alpha;
#pragma unroll
            for (int r = 0; r < 4; ++r) {
                float ar = __shfl(alpha, g * 4 + r);
#pragma unroll
                for (int dt = 0; dt < 4; ++dt) acc[dt][r] *= ar;
            }
        }
        float ts = 0.f;
#pragma unroll
        for (int j = 0; j < 8; ++j) { sv[j] = __expf(sv[j] - mrun); ts += sv[j]; }
        ts += __shfl_xor(ts, 16);
        ts += __shfl_xor(ts, 32);
        lrun += ts;

        uint2 u0; u0.x = pk2(sv[0], sv[1]); u0.y = pk2(sv[2], sv[3]);
        uint2 u1; u1.x = pk2(sv[4], sv[5]); u1.y = pk2(sv[6], sv[7]);
        *(uint2*)&Pl[wave][r16][g * 4] = u0;
        *(uint2*)&Pl[wave][r16][16 + g * 4] = u1;
        bf16x8 pf = *(const bf16x8*)&Pl[wave][r16][g * 8];
#pragma unroll
        for (int dt = 0; dt < 4; ++dt) {
            bf16x8 vf = *(const bf16x8*)(vb + (dt * 16 + r16) * 32 + g * 8);
            acc[dt] = mfma16(pf, vf, acc[dt]);
        }
        __syncthreads();
    }

    float* Op = p ? O1 : O0;
    if (lane < 16)
        ML[(size_t)p * 32768 + (size_t)bh * 1024 + q0 + lane] = make_float2(mrun, lrun);
    const size_t obase = ((size_t)bh * 1024 + q0) * 64;
#pragma unroll
    for (int dt = 0; dt < 4; ++dt)
#pragma unroll
        for (int r = 0; r < 4; ++r)
            Op[obase + (size_t)(g * 4 + r) * 64 + dt * 16 + r16] = acc[dt][r];
}

// ---------------------------------------------------------------- attention combine
__global__ __launch_bounds__(256) void attn_combine_kernel(
    const float* __restrict__ O0, const float* __restrict__ O1,
    const float2* __restrict__ ML, u16* __restrict__ O) {
    int idx = blockIdx.x * 256 + threadIdx.x;   // row*64 + d
    int row = idx >> 6, d = idx & 63;
    float2 a = ML[row], c = ML[32768 + row];
    float M = fmaxf(a.x, c.x);
    float w0 = __expf(a.x - M), w1 = __expf(c.x - M);
    float den = a.y * w0 + c.y * w1;
    float v = (O0[idx] * w0 + O1[idx] * w1) / den;
    int bh = row >> 10, q = row & 1023;
    int b = bh >> 3, h = bh & 7;
    O[((size_t)(b * 1024 + q)) * 512 + h * 64 + d] = f2bf(v);
}

// ---------------------------------------------------------------- LayerNorm
template <int MODE>
__global__ __launch_bounds__(256) void ln_kernel(
    const float* __restrict__ a, const float* __restrict__ bsrc,
    const float* __restrict__ gam, const float* __restrict__ bet,
    const float* __restrict__ pos,
    float* __restrict__ yf, u16* __restrict__ yb, u16* __restrict__ qb) {
    const int lane = threadIdx.x & 63;
    const int row = blockIdx.x * 4 + (threadIdx.x >> 6);
    const size_t base = (size_t)row * 512 + lane * 8;
    float4 av0 = ((const float4*)(a + base))[0];
    float4 av1 = ((const float4*)(a + base))[1];
    float4 bv0 = ((const float4*)(bsrc + base))[0];
    float4 bv1 = ((const float4*)(bsrc + base))[1];
    float x[8] = {av0.x + bv0.x, av0.y + bv0.y, av0.z + bv0.z, av0.w + bv0.w,
                  av1.x + bv1.x, av1.y + bv1.y, av1.z + bv1.z, av1.w + bv1.w};
    float s1 = 0.f, s2 = 0.f;
#pragma unroll
    for (int j = 0; j < 8; ++j) { s1 += x[j]; s2 += x[j] * x[j]; }
#pragma unroll
    for (int d = 1; d < 64; d <<= 1) { s1 += __shfl_xor(s1, d); s2 += __shfl_xor(s2, d); }
    float mean = s1 * (1.f / 512.f);
    float var = s2 * (1.f / 512.f) - mean * mean;
    float rs = rsqrtf(var + 1e-5f);
    float4 gv0 = ((const float4*)(gam + lane * 8))[0];
    float4 gv1 = ((const float4*)(gam + lane * 8))[1];
    float4 be0 = ((const float4*)(bet + lane * 8))[0];
    float4 be1 = ((const float4*)(bet + lane * 8))[1];
    float gg[8] = {gv0.x, gv0.y, gv0.z, gv0.w, gv1.x, gv1.y, gv1.z, gv1.w};
    float bb[8] = {be0.x, be0.y, be0.z, be0.w, be1.x, be1.y, be1.z, be1.w};
    float y[8];
#pragma unroll
    for (int j = 0; j < 8; ++j) y[j] = (x[j] - mean) * rs * gg[j] + bb[j];
    ((float4*)(yf + base))[0] = make_float4(y[0], y[1], y[2], y[3]);
    ((float4*)(yf + base))[1] = make_float4(y[4], y[5], y[6], y[7]);
    if (MODE <= 1) {
        ((ushort4*)(yb + base))[0] = make_ushort4(f2bf(y[0]), f2bf(y[1]), f2bf(y[2]), f2bf(y[3]));
        ((ushort4*)(yb + base))[1] = make_ushort4(f2bf(y[4]), f2bf(y[5]), f2bf(y[6]), f2bf(y[7]));
    }
    if (MODE == 0) {
        float4 p0 = ((const float4*)(pos + base))[0];
        float4 p1 = ((const float4*)(pos + base))[1];
        ((ushort4*)(qb + base))[0] = make_ushort4(f2bf(y[0] + p0.x), f2bf(y[1] + p0.y),
                                                  f2bf(y[2] + p0.z), f2bf(y[3] + p0.w));
        ((ushort4*)(qb + base))[1] = make_ushort4(f2bf(y[4] + p1.x), f2bf(y[5] + p1.y),
                                                  f2bf(y[6] + p1.z), f2bf(y[7] + p1.w));
    }
}

// ---------------------------------------------------------------- host
extern "C" void kernel_launch(void* const* d_in, const int* in_sizes, int n_in,
                              void* d_out, int out_size, void* d_ws, size_t ws_size,
                              hipStream_t stream) {
    (void)in_sizes; (void)n_in; (void)out_size; (void)ws_size;
    const float* tgt      = (const float*)d_in[0];
    const float* memory   = (const float*)d_in[1];
    const float* tgt_pos  = (const float*)d_in[2];
    const float* mem_pos  = (const float*)d_in[3];
    const int*   tgt_mask = (const int*)d_in[4];
    const int*   mem_mask = (const int*)d_in[5];
    const float* sa_b[4] = {(const float*)d_in[7], (const float*)d_in[9],
                            (const float*)d_in[11], (const float*)d_in[13]};
    const float* ca_b[4] = {(const float*)d_in[15], (const float*)d_in[17],
                            (const float*)d_in[19], (const float*)d_in[21]};
    const float* ln1_g = (const float*)d_in[22]; const float* ln1_b = (const float*)d_in[23];
    const float* ln2_g = (const float*)d_in[24]; const float* ln2_b = (const float*)d_in[25];
    const float* ln3_g = (const float*)d_in[26]; const float* ln3_b = (const float*)d_in[27];
    const float* mlp_b1 = (const float*)d_in[29];
    const float* mlp_b2 = (const float*)d_in[31];

    const size_t MiB = 1024 * 1024;
    char* ws = (char*)d_ws;
    u16*  WT  = (u16*)(ws + 0);
    u32*  MBS = (u32*)(ws + 8 * MiB);
    u32*  MBC = (u32*)(ws + 8 * MiB + 512 * 1024);
    u16*  QIN = (u16*)(ws + 9 * MiB);
    u16*  TGTB= (u16*)(ws + 13 * MiB);
    u16*  MEMB= (u16*)(ws + 17 * MiB);
    u16*  MKB = (u16*)(ws + 21 * MiB);
    u16*  QM  = (u16*)(ws + 25 * MiB);
    u16*  KM  = (u16*)(ws + 29 * MiB);
    u16*  VM  = (u16*)(ws + 33 * MiB);
    u16*  VTM = (u16*)(ws + 37 * MiB);
    u16*  ATNB= (u16*)(ws + 41 * MiB);
    float* PROJ= (float*)(ws + 45 * MiB);   // 8MB; doubles as attn partial O0
    float* X1F = (float*)(ws + 53 * MiB);
    u16*  X1B = (u16*)(ws + 61 * MiB);
    u16*  MQB = (u16*)(ws + 65 * MiB);
    float* X2F = (float*)(ws + 69 * MiB);   // 8MB; doubles as attn partial O1
    u16*  X2B = (u16*)(ws + 77 * MiB);      // first 512KB doubles as attn ML
    u16*  FFH = (u16*)(ws + 9 * MiB);
    float* OP0 = PROJ;
    float* OP1 = X2F;
    float2* MLB = (float2*)(ws + 77 * MiB);

    u16* wt[10];
    for (int z = 0; z < 8; ++z) wt[z] = WT + (size_t)z * 262144;
    wt[8] = WT + 2097152;
    wt[9] = WT + 3145728;

    W10 w10;
    w10.w[0] = (const float*)d_in[6];  w10.w[1] = (const float*)d_in[8];
    w10.w[2] = (const float*)d_in[10]; w10.w[3] = (const float*)d_in[12];
    w10.w[4] = (const float*)d_in[14]; w10.w[5] = (const float*)d_in[16];
    w10.w[6] = (const float*)d_in[18]; w10.w[7] = (const float*)d_in[20];
    w10.w[8] = (const float*)d_in[28]; w10.w[9] = (const float*)d_in[30];
    wtrans_kernel<<<dim3(1024, 10), dim3(32, 8), 0, stream>>>(w10, WT);

    packmask_kernel<<<32768, 256, 0, stream>>>(tgt_mask, mem_mask, MBS, MBC, 4 * 1024 * 1024);

    prep_kernel<<<2048, 256, 0, stream>>>(
        (const float4*)tgt, (const float4*)tgt_pos, (const float4*)memory, (const float4*)mem_pos,
        (ushort4*)QIN, (ushort4*)TGTB, (ushort4*)MEMB, (ushort4*)MKB, 524288);

    GemmArgs3 ga;
    // SA q,k,v projections (Q pre-scaled by 1/8)
    ga.s[0] = {QIN,  wt[0], sa_b[0], QM, 0.125f};
    ga.s[1] = {QIN,  wt[1], sa_b[1], KM, 1.f};
    ga.s[2] = {TGTB, wt[2], sa_b[2], VM, 1.f};
    gemm_kernel<0, 128><<<dim3(8, 32, 3), 256, 0, stream>>>(ga, 4096, 512, 512);
    vtrans_kernel<<<dim3(32, 2, 32), dim3(32, 8), 0, stream>>>(VM, VTM, 1024);
    attn_part_kernel<<<dim3(16, 8, 8), 256, 0, stream>>>(QM, KM, VTM, MBS, OP0, OP1, MLB, 1024, 1024);
    attn_combine_kernel<<<8192, 256, 0, stream>>>(OP0, OP1, MLB, ATNB);
    ga.s[0] = {ATNB, wt[3], sa_b[3], PROJ, 1.f}; ga.s[1] = ga.s[0]; ga.s[2] = ga.s[0];
    gemm_kernel<2, 64><<<dim3(8, 64, 1), 256, 0, stream>>>(ga, 4096, 512, 512);
    ln_kernel<0><<<1024, 256, 0, stream>>>(tgt, PROJ, ln1_g, ln1_b, tgt_pos, X1F, X1B, MQB);

    // CA q,k,v projections
    ga.s[0] = {MQB,  wt[4], ca_b[0], QM, 0.125f};
    ga.s[1] = {MKB,  wt[5], ca_b[1], KM, 1.f};
    ga.s[2] = {MEMB, wt[6], ca_b[2], VM, 1.f};
    gemm_kernel<0, 128><<<dim3(8, 32, 3), 256, 0, stream>>>(ga, 4096, 512, 512);
    vtrans_kernel<<<dim3(32, 2, 32), dim3(32, 8), 0, stream>>>(VM, VTM, 1024);
    attn_part_kernel<<<dim3(16, 8, 8), 256, 0, stream>>>(QM, KM, VTM, MBC, OP0, OP1, MLB, 1024, 1024);
    attn_combine_kernel<<<8192, 256, 0, stream>>>(OP0, OP1, MLB, ATNB);
    ga.s[0] = {ATNB, wt[7], ca_b[3], PROJ, 1.f}; ga.s[1] = ga.s[0]; ga.s[2] = ga.s[0];
    gemm_kernel<2, 64><<<dim3(8, 64, 1), 256, 0, stream>>>(ga, 4096, 512, 512);
    ln_kernel<1><<<1024, 256, 0, stream>>>(X1F, PROJ, ln2_g, ln2_b, nullptr, X2F, X2B, nullptr);

    // FFN
    ga.s[0] = {X2B, wt[8], mlp_b1, FFH, 1.f}; ga.s[1] = ga.s[0]; ga.s[2] = ga.s[0];
    gemm_kernel<1, 128><<<dim3(32, 32, 1), 256, 0, stream>>>(ga, 4096, 2048, 512);
    ga.s[0] = {FFH, wt[9], mlp_b2, PROJ, 1.f}; ga.s[1] = ga.s[0]; ga.s[2] = ga.s[0];
    gemm_kernel<2, 64><<<dim3(8, 64, 1), 256, 0, stream>>>(ga, 4096, 512, 2048);
    ln_kernel<2><<<1024, 256, 0, stream>>>(X2F, PROJ, ln3_g, ln3_b, nullptr,
                                           (float*)d_out, nullptr, nullptr);
}